// Round 11
// baseline (52.061 us; speedup 1.0000x reference)
//
#include <hip/hip_runtime.h>
#include <hip/hip_bf16.h>

#define HWDIM 512
#define NWIN 50        // windows per dim: (512-20)/10 + 1
#define NT 51          // 10x10 tiles per dim covering rows/cols 0..509
#define NBC 48         // B*C = 16*3
#define NSTRIPE (NBC * NT)   // 2448 blocks, 1 stripe each
#define EPSV 1e-5f

// ws layout: int cnt[49] (48 plane counters + 1 global); floats [64..111] acc[48];
//            [128..] tiles4[48*51*51] float4 (sc-published, ~2.0 MB)

union F2U { float2 f; unsigned long long u; };

__global__ void zero_kernel(int* cnt) {
    int t = threadIdx.x;
    if (t < NBC + 1) cnt[t] = 0;
}

// ---------------------------------------------------------------------------
// Fused: tile sums -> publish via agent-scope (sc) stores -> last stripe-block
// per plane does the window phase -> last plane does the 48-way mean.
// NO __threadfence anywhere (R4 lesson: 2448 cache-maintenance ops collapse
// the concurrently-running blocks' cache hit rate). Visibility discipline:
//   writers: sc-stores complete at device-coherent point; s_waitcnt vmcnt(0)
//            (same-wave: all publishing lanes are in wave 0) BEFORE the
//            relaxed agent fetch_add on the plane counter.
//   readers: relaxed agent atomic loads (bypass stale L1/L2, no invalidate).
// Tile math identical to R5-R8 (absmax 0.0 proven).
// ---------------------------------------------------------------------------
__global__ __launch_bounds__(256) void fused_kernel(const float* __restrict__ C,
                                                    const float* __restrict__ E,
                                                    const float* __restrict__ M,
                                                    float4* __restrict__ tiles4,
                                                    int* __restrict__ cnt,
                                                    float* __restrict__ acc,
                                                    float* __restrict__ out) {
    int t     = threadIdx.x;
    int blk   = blockIdx.x;        // stripe id = plane*NT + ty
    int plane = blk / NT;
    int ty    = blk % NT;
    int c4    = t & 127;
    int rh    = t >> 7;
    bool isf2 = ((c4 % 5) == 2);

    size_t base = ((size_t)plane * HWDIM + (size_t)ty * 10 + rh) * HWDIM + 4 * c4;

    float4 cv[5], ev[5], mv[5];
    #pragma unroll
    for (int it = 0; it < 5; ++it) {
        size_t o = base + (size_t)(2 * it) * HWDIM;
        cv[it] = *(const float4*)(C + o);
        ev[it] = *(const float4*)(E + o);
        mv[it] = *(const float4*)(M + o);
    }

    float s01[3] = {0.f, 0.f, 0.f};
    float s23[3] = {0.f, 0.f, 0.f};
    #pragma unroll
    for (int it = 0; it < 5; ++it) {
        float4 c = cv[it], e = ev[it], m = mv[it];
        float mcx = m.x * c.x, mcy = m.y * c.y, mcz = m.z * c.z, mcw = m.w * c.w;
        float mex = m.x * e.x, mey = m.y * e.y, mez = m.z * e.z, mew = m.w * e.w;
        s01[0] = fmaf(mcx, c.x, s01[0]); s01[0] = fmaf(mcy, c.y, s01[0]);
        s01[1] = fmaf(mcx, e.x, s01[1]); s01[1] = fmaf(mcy, e.y, s01[1]);
        s01[2] = fmaf(mex, e.x, s01[2]); s01[2] = fmaf(mey, e.y, s01[2]);
        s23[0] = fmaf(mcz, c.z, s23[0]); s23[0] = fmaf(mcw, c.w, s23[0]);
        s23[1] = fmaf(mcz, e.z, s23[1]); s23[1] = fmaf(mcw, e.w, s23[1]);
        s23[2] = fmaf(mez, e.z, s23[2]); s23[2] = fmaf(mew, e.w, s23[2]);
    }

    __shared__ float lds[256 * 6];
    #pragma unroll
    for (int comp = 0; comp < 3; ++comp) {
        float lo = s01[comp] + (isf2 ? 0.f : s23[comp]);
        float hi = isf2 ? s23[comp] : 0.f;
        lds[t * 6 + comp]     = lo;
        lds[t * 6 + 3 + comp] = hi;
    }
    __syncthreads();

    if (t < NT) {                  // 51 lanes of wave 0: publish one tile each
        int tx = t;
        int k  = tx >> 1;
        float sums[3];
        #pragma unroll
        for (int comp = 0; comp < 3; ++comp) {
            float s;
            if ((tx & 1) == 0) {
                int b = 5 * k;
                s = lds[b * 6 + comp] + lds[(b + 1) * 6 + comp] + lds[(b + 2) * 6 + comp]
                  + lds[(b + 128) * 6 + comp] + lds[(b + 129) * 6 + comp] + lds[(b + 130) * 6 + comp];
            } else {
                int b = 5 * k + 2;
                s = lds[b * 6 + 3 + comp] + lds[(b + 1) * 6 + comp] + lds[(b + 2) * 6 + comp]
                  + lds[(b + 128) * 6 + 3 + comp] + lds[(b + 129) * 6 + comp] + lds[(b + 130) * 6 + comp];
            }
            sums[comp] = s;
        }
        F2U lo, hi;
        lo.f = make_float2(sums[0], sums[1]);
        hi.f = make_float2(sums[2], 0.f);
        unsigned long long* p = (unsigned long long*)&tiles4[(size_t)blk * NT + tx];
        __hip_atomic_store(p,     lo.u, __ATOMIC_RELAXED, __HIP_MEMORY_SCOPE_AGENT);
        __hip_atomic_store(p + 1, hi.u, __ATOMIC_RELAXED, __HIP_MEMORY_SCOPE_AGENT);
    }
    asm volatile("s_waitcnt vmcnt(0)" ::: "memory");   // wave-0 drains its sc-stores
    __syncthreads();

    __shared__ int sflag;
    if (t == 0)
        sflag = (__hip_atomic_fetch_add(&cnt[plane], 1, __ATOMIC_RELAXED,
                                        __HIP_MEMORY_SCOPE_AGENT) == NT - 1);
    __syncthreads();
    if (!sflag) return;

    // ---- window phase (last stripe-block of this plane) ----
    __shared__ float4 lt[NT * NT];               // 41616 B
    const unsigned long long* tp =
        (const unsigned long long*)(tiles4 + (size_t)plane * NT * NT);
    #pragma unroll
    for (int k = 0; k < 11; ++k) {               // 11*256 >= 2601
        int i = t + k * 256;
        if (i < NT * NT) {
            F2U a, b;
            a.u = __hip_atomic_load(tp + 2 * i,     __ATOMIC_RELAXED, __HIP_MEMORY_SCOPE_AGENT);
            b.u = __hip_atomic_load(tp + 2 * i + 1, __ATOMIC_RELAXED, __HIP_MEMORY_SCOPE_AGENT);
            lt[i] = make_float4(a.f.x, a.f.y, b.f.x, b.f.y);
        }
    }
    __syncthreads();

    float ssq = 0.0f, tot = 0.0f;
    #pragma unroll
    for (int k = 0; k < 10; ++k) {               // 10*256 >= 2500
        int w = t + k * 256;
        if (w < NWIN * NWIN) {
            int wy = w / NWIN, wx = w % NWIN;
            float4 a = lt[wy * NT + wx];
            float4 b = lt[wy * NT + wx + 1];
            float4 c = lt[(wy + 1) * NT + wx];
            float4 d = lt[(wy + 1) * NT + wx + 1];
            float s_cc = a.x + b.x + c.x + d.x;
            float s_ce = a.y + b.y + c.y + d.y;
            float s_ee = a.z + b.z + c.z + d.z;
            float a2v = (s_ee > EPSV) ? (s_ce * s_ce / s_ee) : 0.0f;
            ssq += s_cc - a2v;
            tot += s_cc;
        }
    }

    #pragma unroll
    for (int d = 1; d < 64; d <<= 1) {
        ssq += __shfl_xor(ssq, d);
        tot += __shfl_xor(tot, d);
    }
    __shared__ float sr[8];
    int lane = t & 63, wave = t >> 6;
    if (lane == 0) { sr[wave] = ssq; sr[4 + wave] = tot; }
    __syncthreads();

    if (t == 0) {
        float S = sr[0] + sr[1] + sr[2] + sr[3];
        float T = sr[4] + sr[5] + sr[6] + sr[7];
        __hip_atomic_store(&acc[plane], S / T, __ATOMIC_RELAXED, __HIP_MEMORY_SCOPE_AGENT);
        asm volatile("s_waitcnt vmcnt(0)" ::: "memory");
        sflag = (__hip_atomic_fetch_add(&cnt[NBC], 1, __ATOMIC_RELAXED,
                                        __HIP_MEMORY_SCOPE_AGENT) == NBC - 1);
    }
    __syncthreads();
    if (!sflag) return;

    // ---- final phase (last plane): deterministic fixed-order 48-way mean ----
    if (t < 64) {
        float r = 0.0f;
        if (t < NBC)
            r = __hip_atomic_load(&acc[t], __ATOMIC_RELAXED, __HIP_MEMORY_SCOPE_AGENT);
        #pragma unroll
        for (int d = 1; d < 64; d <<= 1) r += __shfl_xor(r, d);
        if (t == 0) out[0] = r / (float)NBC;
    }
}

extern "C" void kernel_launch(void* const* d_in, const int* in_sizes, int n_in,
                              void* d_out, int out_size, void* d_ws, size_t ws_size,
                              hipStream_t stream) {
    const float* correct  = (const float*)d_in[0];
    const float* estimate = (const float*)d_in[1];
    const float* mask     = (const float*)d_in[2];
    float* out = (float*)d_out;

    int*    cnt    = (int*)d_ws;                    // 49 ints
    float*  acc    = (float*)d_ws + 64;             // 48 floats
    float4* tiles4 = (float4*)((float*)d_ws + 128); // 48*51*51 float4 ~ 2.0 MB

    zero_kernel<<<1, 64, 0, stream>>>(cnt);
    fused_kernel<<<NSTRIPE, 256, 0, stream>>>(correct, estimate, mask,
                                              tiles4, cnt, acc, out);
}

// Round 12
// 36.690 us; speedup vs baseline: 1.4189x; 1.4189x over previous
//
#include <hip/hip_runtime.h>
#include <hip/hip_bf16.h>

#define HWDIM 512
#define NWIN 50        // windows per dim: (512-20)/10 + 1
#define NT 51          // 10x10 tiles per dim covering rows/cols 0..509
#define NBC 48         // B*C = 16*3
#define EPSV 1e-5f

// ---------------------------------------------------------------------------
// Pass 1: per-(plane, 10-row stripe) tile sums, float4 loads, batched MLP.
// Thread t: col4 = t&127 (cols 4*col4 .. 4*col4+3), row-half rh = t>>7.
// Rows processed: 2*it + rh, it = 0..4  (covers the stripe's 10 rows).
// Tile split: pattern repeats every 5 float4s (20 cols = 2 tiles);
// f = col4 % 5: f=0,1 -> all 4 cols in tile 2k; f=2 -> cols 0,1 in tile 2k,
// cols 2,3 in tile 2k+1; f=3,4 -> all 4 in tile 2k+1.  (k = col4/5)
// Output: tiles[(blk*NT + tx)*3 + {0,1,2}] = (sum m*c*c, m*c*e, m*e*e).
// ---------------------------------------------------------------------------
__global__ __launch_bounds__(256) void tile_kernel(const float* __restrict__ C,
                                                   const float* __restrict__ E,
                                                   const float* __restrict__ M,
                                                   float* __restrict__ tiles) {
    int blk   = blockIdx.x;        // plane*NT + ty
    int plane = blk / NT;
    int ty    = blk % NT;
    int t     = threadIdx.x;
    int c4    = t & 127;
    int rh    = t >> 7;
    int f     = c4 % 5;
    bool isf2 = (f == 2);

    size_t base = ((size_t)plane * HWDIM + (size_t)ty * 10 + rh) * HWDIM + 4 * c4;

    float4 cv[5], ev[5], mv[5];
    #pragma unroll
    for (int it = 0; it < 5; ++it) {
        size_t o = base + (size_t)(2 * it) * HWDIM;
        cv[it] = *(const float4*)(C + o);
        ev[it] = *(const float4*)(E + o);
        mv[it] = *(const float4*)(M + o);
    }
    __builtin_amdgcn_sched_barrier(0);

    float s01[3] = {0.f, 0.f, 0.f};
    float s23[3] = {0.f, 0.f, 0.f};
    #pragma unroll
    for (int it = 0; it < 5; ++it) {
        float4 c = cv[it], e = ev[it], m = mv[it];
        float mcx = m.x * c.x, mcy = m.y * c.y, mcz = m.z * c.z, mcw = m.w * c.w;
        float mex = m.x * e.x, mey = m.y * e.y, mez = m.z * e.z, mew = m.w * e.w;
        s01[0] = fmaf(mcx, c.x, s01[0]); s01[0] = fmaf(mcy, c.y, s01[0]);
        s01[1] = fmaf(mcx, e.x, s01[1]); s01[1] = fmaf(mcy, e.y, s01[1]);
        s01[2] = fmaf(mex, e.x, s01[2]); s01[2] = fmaf(mey, e.y, s01[2]);
        s23[0] = fmaf(mcz, c.z, s23[0]); s23[0] = fmaf(mcw, c.w, s23[0]);
        s23[1] = fmaf(mcz, e.z, s23[1]); s23[1] = fmaf(mcw, e.w, s23[1]);
        s23[2] = fmaf(mez, e.z, s23[2]); s23[2] = fmaf(mew, e.w, s23[2]);
    }

    __shared__ float lds[256 * 6];
    #pragma unroll
    for (int comp = 0; comp < 3; ++comp) {
        float lo = s01[comp] + (isf2 ? 0.f : s23[comp]);
        float hi = isf2 ? s23[comp] : 0.f;
        lds[t * 6 + comp]     = lo;
        lds[t * 6 + 3 + comp] = hi;
    }
    __syncthreads();

    if (t < NT * 3) {              // 153 threads: one per (tile, component)
        int tx = t / 3, comp = t % 3;
        int k  = tx >> 1;
        float s;
        if ((tx & 1) == 0) {
            int b = 5 * k;
            s = lds[b * 6 + comp] + lds[(b + 1) * 6 + comp] + lds[(b + 2) * 6 + comp]
              + lds[(b + 128) * 6 + comp] + lds[(b + 129) * 6 + comp] + lds[(b + 130) * 6 + comp];
        } else {
            int b = 5 * k + 2;
            s = lds[b * 6 + 3 + comp] + lds[(b + 1) * 6 + comp] + lds[(b + 2) * 6 + comp]
              + lds[(b + 128) * 6 + 3 + comp] + lds[(b + 129) * 6 + comp] + lds[(b + 130) * 6 + comp];
        }
        tiles[((size_t)blk * NT + tx) * 3 + comp] = s;
    }
}

// ---------------------------------------------------------------------------
// Pass 2: per-plane window combine. Window (wy,wx) = 4 tiles.
// ---------------------------------------------------------------------------
__global__ __launch_bounds__(256) void window_kernel(const float* __restrict__ tiles,
                                                     float* __restrict__ acc) {
    int plane = blockIdx.x;
    const float* tp = tiles + (size_t)plane * NT * NT * 3;

    float ssq = 0.0f, tot = 0.0f;
    for (int w = threadIdx.x; w < NWIN * NWIN; w += 256) {
        int wy = w / NWIN, wx = w % NWIN;
        const float* t00 = tp + ((size_t)wy * NT + wx) * 3;
        const float* t10 = t00 + (size_t)NT * 3;
        float s_cc = t00[0] + t00[3] + t10[0] + t10[3];
        float s_ce = t00[1] + t00[4] + t10[1] + t10[4];
        float s_ee = t00[2] + t00[5] + t10[2] + t10[5];
        float a2v = (s_ee > EPSV) ? (s_ce * s_ce / s_ee) : 0.0f;
        ssq += s_cc - a2v;
        tot += s_cc;
    }

    #pragma unroll
    for (int d = 1; d < 64; d <<= 1) {
        ssq += __shfl_xor(ssq, d);
        tot += __shfl_xor(tot, d);
    }
    __shared__ float sr[8];
    int lane = threadIdx.x & 63, wave = threadIdx.x >> 6;
    if (lane == 0) { sr[wave] = ssq; sr[4 + wave] = tot; }
    __syncthreads();
    if (threadIdx.x == 0) {
        float S = sr[0] + sr[1] + sr[2] + sr[3];
        float T = sr[4] + sr[5] + sr[6] + sr[7];
        acc[plane] = S / T;
    }
}

__global__ void final_kernel(const float* __restrict__ acc, float* __restrict__ out) {
    int lane = threadIdx.x;
    float r = (lane < NBC) ? acc[lane] : 0.0f;
    #pragma unroll
    for (int d = 1; d < 64; d <<= 1) r += __shfl_xor(r, d);
    if (lane == 0) out[0] = r / (float)NBC;
}

extern "C" void kernel_launch(void* const* d_in, const int* in_sizes, int n_in,
                              void* d_out, int out_size, void* d_ws, size_t ws_size,
                              hipStream_t stream) {
    const float* correct  = (const float*)d_in[0];
    const float* estimate = (const float*)d_in[1];
    const float* mask     = (const float*)d_in[2];
    float* out = (float*)d_out;

    float* acc   = (float*)d_ws;                 // 48 floats
    float* tiles = (float*)d_ws + 64;            // 48*51*51*3 floats ≈ 1.5 MB

    tile_kernel<<<NBC * NT, 256, 0, stream>>>(correct, estimate, mask, tiles);
    window_kernel<<<NBC, 256, 0, stream>>>(tiles, acc);
    final_kernel<<<1, 64, 0, stream>>>(acc, out);
}